// Round 1
// baseline (235.679 us; speedup 1.0000x reference)
//
#include <hip/hip_runtime.h>

// ---------------- problem constants ----------------
#define N13E 16224      // 32*3*169
#define N26E 64896      // 32*3*676
#define N52E 259584     // 32*3*2704
#define NTOT 340704
#define BASE26 16224
#define BASE52 81120
#define KMAX 2048       // compaction capacity (power of 2 for bitonic)
#define TOPK 512

__device__ __forceinline__ float sigm(float x) { return 1.0f / (1.0f + expf(-x)); }

// ---------------- K1: init ----------------
__global__ void k_init(unsigned* __restrict__ hist, unsigned* __restrict__ cnt) {
    int t = threadIdx.x;
    for (int i = t; i < 2048; i += 256) hist[i] = 0u;
    if (t == 0) *cnt = 0u;
}

// ---------------- K2: histogram of conf bits ----------------
template <int HW>
__device__ __forceinline__ float load_logit(const float* __restrict__ p, int local) {
    int ba = local / HW;           // b*3 + a
    int hw = local - ba * HW;
    int b = ba / 3;
    int a = ba - b * 3;
    return p[(b * 255 + a * 85 + 4) * HW + hw];
}

__global__ void k_hist(const float* __restrict__ p13, const float* __restrict__ p26,
                       const float* __restrict__ p52, unsigned* __restrict__ hist) {
    int t = blockIdx.x * 256 + threadIdx.x;
    if (t >= NTOT) return;
    float logit;
    if (t < N13E)               logit = load_logit<169>(p13, t);
    else if (t < N13E + N26E)   logit = load_logit<676>(p26, t - N13E);
    else                        logit = load_logit<2704>(p52, t - (N13E + N26E));
    float conf = sigm(logit);
    if (conf > 0.5f) {
        unsigned bin = (__float_as_uint(conf) >> 12) - 0x3F000u;
        bin = (bin > 2047u) ? 2047u : bin;
        atomicAdd(&hist[bin], 1u);
    }
}

// ---------------- K3: suffix scan -> bit threshold ----------------
__global__ void k_scan(const unsigned* __restrict__ hist, unsigned* __restrict__ thr) {
    __shared__ unsigned tot[256];
    int t = threadIdx.x;
    unsigned loc[8]; unsigned s = 0u;
#pragma unroll
    for (int k = 0; k < 8; ++k) { loc[k] = hist[2047 - (t * 8 + k)]; s += loc[k]; }
    tot[t] = s;
    __syncthreads();
    for (int off = 1; off < 256; off <<= 1) {
        unsigned u = (t >= off) ? tot[t - off] : 0u;
        __syncthreads();
        tot[t] += u;
        __syncthreads();
    }
    unsigned excl = tot[t] - s;
    unsigned total = tot[255];
    if (total < (unsigned)TOPK) {
        if (t == 0) *thr = 0x3F000001u;   // accept every conf > 0.5
    } else {
        unsigned run = excl;
#pragma unroll
        for (int k = 0; k < 8; ++k) {
            unsigned c = run + loc[k];
            if (run < (unsigned)TOPK && c >= (unsigned)TOPK) {
                int bin = 2047 - (t * 8 + k);
                *thr = ((unsigned)(bin + 0x3F000)) << 12;
            }
            run = c;
        }
    }
}

// ---------------- K4: compact keys ----------------
template <int HW, int BASE>
__device__ __forceinline__ void compact_one(const float* __restrict__ p, int local, unsigned thrv,
                                            unsigned* __restrict__ cnt,
                                            unsigned long long* __restrict__ keys) {
    int ba = local / HW;
    int hw = local - ba * HW;
    int b = ba / 3;
    int a = ba - b * 3;
    float logit = p[(b * 255 + a * 85 + 4) * HW + hw];
    float conf = sigm(logit);
    unsigned bits = __float_as_uint(conf);
    if (conf > 0.5f && bits >= thrv) {
        unsigned pos = atomicAdd(cnt, 1u);
        if (pos < (unsigned)KMAX) {
            unsigned concat = (unsigned)(BASE + (b * HW + hw) * 3 + a);
            keys[pos] = (((unsigned long long)bits) << 32) | (unsigned long long)(0xFFFFFFFFu - concat);
        }
    }
}

__global__ void k_compact(const float* __restrict__ p13, const float* __restrict__ p26,
                          const float* __restrict__ p52, const unsigned* __restrict__ thrp,
                          unsigned* __restrict__ cnt, unsigned long long* __restrict__ keys) {
    int t = blockIdx.x * 256 + threadIdx.x;
    if (t >= NTOT) return;
    unsigned thrv = *thrp;
    if (t < N13E)               compact_one<169, 0>(p13, t, thrv, cnt, keys);
    else if (t < N13E + N26E)   compact_one<676, BASE26>(p26, t - N13E, thrv, cnt, keys);
    else                        compact_one<2704, BASE52>(p52, t - (N13E + N26E), thrv, cnt, keys);
}

// ---------------- K5: bitonic sort 2048, keep top 512 ----------------
__global__ void __launch_bounds__(1024) k_sort(const unsigned* __restrict__ cnt,
                                               const unsigned long long* __restrict__ keys,
                                               unsigned long long* __restrict__ sorted) {
    __shared__ unsigned long long sk[KMAX];
    int t = threadIdx.x;
    unsigned n = *cnt; if (n > (unsigned)KMAX) n = (unsigned)KMAX;
    sk[t]        = ((unsigned)t < n)          ? keys[t]        : 0ull;
    sk[t + 1024] = ((unsigned)(t + 1024) < n) ? keys[t + 1024] : 0ull;
    for (unsigned size = 2; size < (unsigned)KMAX; size <<= 1) {
        unsigned ddd = ((t & (int)(size >> 1)) != 0) ? 1u : 0u;
        for (unsigned stride = size >> 1; stride > 0; stride >>= 1) {
            __syncthreads();
            unsigned pos = 2u * (unsigned)t - ((unsigned)t & (stride - 1u));
            unsigned long long a = sk[pos], b = sk[pos + stride];
            if ((unsigned)(a > b) == ddd) { sk[pos] = b; sk[pos + stride] = a; }
        }
    }
    for (unsigned stride = KMAX / 2; stride > 0; stride >>= 1) {  // final merge, descending
        __syncthreads();
        unsigned pos = 2u * (unsigned)t - ((unsigned)t & (stride - 1u));
        unsigned long long a = sk[pos], b = sk[pos + stride];
        if (a < b) { sk[pos] = b; sk[pos + stride] = a; }
    }
    __syncthreads();
    if (t < TOPK) sorted[t] = sk[t];
}

// ---------------- K6: decode selected boxes ----------------
__device__ __forceinline__ unsigned long long pack_key(float v, int c) {
    unsigned u = __float_as_uint(v);
    unsigned ov = (u & 0x80000000u) ? ~u : (u | 0x80000000u);
    return (((unsigned long long)ov) << 32) | (unsigned long long)(unsigned)(127 - c);
}

template <int HW, int W>
__device__ __forceinline__ void decode_one(const float* __restrict__ p, int local, float strideF,
                                           float aw0, float ah0, float aw1, float ah1, float aw2, float ah2,
                                           float conf, float* __restrict__ outrow, int lane) {
    int a = local % 3;
    int cell = local / 3;
    int b = cell / HW;
    int hw = cell - b * HW;
    int h = hw / W;
    int wc = hw - h * W;
    int cb = b * 255 + a * 85;
    // class argmax across the wave (first-index tie-break)
    float v1 = p[(cb + 5 + lane) * HW + hw];
    unsigned long long k1 = pack_key(v1, lane);
    if (lane < 16) {
        float v2 = p[(cb + 69 + lane) * HW + hw];   // classes 64..79
        unsigned long long k2 = pack_key(v2, lane + 64);
        if (k2 > k1) k1 = k2;
    }
#pragma unroll
    for (int m = 32; m >= 1; m >>= 1) {
        unsigned long long o = __shfl_xor(k1, m, 64);
        if (o > k1) k1 = o;
    }
    if (lane == 0) {
        int cls = 127 - (int)(unsigned)(k1 & 0xFFFFFFFFull);
        float t0 = p[(cb + 0) * HW + hw];
        float t1 = p[(cb + 1) * HW + hw];
        float t2 = p[(cb + 2) * HW + hw];
        float t3 = p[(cb + 3) * HW + hw];
        float aw = (a == 0) ? aw0 : ((a == 1) ? aw1 : aw2);
        float ah = (a == 0) ? ah0 : ((a == 1) ? ah1 : ah2);
        float sx = sigm(t0);
        float sy = sigm(t1);
        float bw = aw * expf(t2);
        float bh = ah * expf(t3);
        float cx = ((float)wc + sx) * strideF;
        float cy = ((float)h + sy) * strideF;
        float w0 = bw * 0.5f, h0 = bh * 0.5f;
        outrow[0] = conf;
        outrow[1] = cx - w0;
        outrow[2] = cy - h0;
        outrow[3] = cx + w0;
        outrow[4] = cy + h0;
        outrow[5] = (float)cls;
        outrow[6] = (float)b;
    }
}

__global__ void k_decode(const float* __restrict__ p13, const float* __restrict__ p26,
                         const float* __restrict__ p52, const unsigned long long* __restrict__ sorted,
                         float* __restrict__ cand) {
    int c = blockIdx.x;
    int lane = threadIdx.x;
    unsigned long long key = sorted[c];
    unsigned sb = (unsigned)(key >> 32);
    float* row = cand + c * 7;
    if (sb == 0u) {                 // padded / invalid
        if (lane < 7) row[lane] = 0.0f;
        return;
    }
    unsigned idx = 0xFFFFFFFFu - (unsigned)(key & 0xFFFFFFFFull);
    float conf = __uint_as_float(sb);
    if (idx < N13E)
        decode_one<169, 13>(p13, (int)idx, 32.0f, 116.f, 90.f, 156.f, 198.f, 373.f, 326.f, conf, row, lane);
    else if (idx < N13E + N26E)
        decode_one<676, 26>(p26, (int)idx - BASE26, 16.0f, 30.f, 61.f, 62.f, 45.f, 59.f, 119.f, conf, row, lane);
    else
        decode_one<2704, 52>(p52, (int)idx - BASE52, 8.0f, 10.f, 13.f, 16.f, 30.f, 33.f, 23.f, conf, row, lane);
}

// ---------------- K7: suppression bitmask (j > i, iou > 0.3) ----------------
__global__ void k_mask(const float* __restrict__ cand, unsigned long long* __restrict__ mask) {
    int wid = blockIdx.x * blockDim.x + threadIdx.x;   // word id 0..4095
    if (wid >= TOPK * 8) return;
    int i = wid >> 3, jw = wid & 7;
    const float* bi = cand + i * 7;
    float x1 = bi[1], y1 = bi[2], x2 = bi[3], y2 = bi[4];
    float ai = fmaxf(x2 - x1, 0.f) * fmaxf(y2 - y1, 0.f);
    unsigned long long m = 0ull;
    int j0 = jw * 64;
#pragma unroll 4
    for (int bj = 0; bj < 64; ++bj) {
        int j = j0 + bj;
        const float* bjp = cand + j * 7;
        float jx1 = bjp[1], jy1 = bjp[2], jx2 = bjp[3], jy2 = bjp[4];
        float aj = fmaxf(jx2 - jx1, 0.f) * fmaxf(jy2 - jy1, 0.f);
        float xx1 = fmaxf(x1, jx1), yy1 = fmaxf(y1, jy1);
        float xx2 = fminf(x2, jx2), yy2 = fminf(y2, jy2);
        float inter = fmaxf(xx2 - xx1, 0.f) * fmaxf(yy2 - yy1, 0.f);
        float iou = inter / (((ai + aj) - inter) + 1e-9f);
        if ((j > i) && (iou > 0.3f)) m |= (1ull << bj);
    }
    mask[wid] = m;
}

// ---------------- K8: serial greedy NMS + masked output ----------------
__global__ void __launch_bounds__(512) k_nms(const float* __restrict__ cand,
                                             const unsigned long long* __restrict__ maskg,
                                             float* __restrict__ out) {
    __shared__ unsigned long long smask[TOPK * 8];
    __shared__ unsigned long long live[8];
    __shared__ unsigned long long keepw[8];
    int tid = threadIdx.x;
    for (int p = tid; p < TOPK * 8; p += 512) smask[p] = maskg[p];
    bool validt = cand[tid * 7] > 0.5f;
    unsigned long long bal = __ballot(validt);
    if ((tid & 63) == 0) live[tid >> 6] = bal;
    __syncthreads();
    if (tid < 64) {
        int lane = tid;
        int lw = lane & 7;                       // word this lane owns
        unsigned long long r = 0ull;             // removed bits for word lw
#pragma unroll
        for (int w = 0; w < 8; ++w) {
            unsigned long long lvw = live[w];
#pragma unroll 8
            for (int b2 = 0; b2 < 64; ++b2) {
                int i = w * 64 + b2;
                unsigned long long rowv = smask[i * 8 + lw];
                unsigned rlo = (unsigned)__builtin_amdgcn_readlane((int)(unsigned)(r & 0xFFFFFFFFull), w);
                unsigned rhi = (unsigned)__builtin_amdgcn_readlane((int)(unsigned)(r >> 32), w);
                unsigned long long rw = (((unsigned long long)rhi) << 32) | (unsigned long long)rlo;
                bool acc = (((lvw >> b2) & 1ull) != 0ull) && (((rw >> b2) & 1ull) == 0ull);
                if (acc) r |= rowv;
            }
        }
        if (lane < 8) keepw[lane] = live[lane] & ~r;
    }
    __syncthreads();
    for (int p = tid; p < TOPK * 7; p += 512) {
        int i = p / 7;
        unsigned long long kb = (keepw[i >> 6] >> (i & 63)) & 1ull;
        out[p] = kb ? cand[p] : 0.0f;
    }
}

// ---------------- launch ----------------
extern "C" void kernel_launch(void* const* d_in, const int* in_sizes, int n_in,
                              void* d_out, int out_size, void* d_ws, size_t ws_size,
                              hipStream_t stream) {
    const float* p13 = (const float*)d_in[0];
    const float* p26 = (const float*)d_in[1];
    const float* p52 = (const float*)d_in[2];
    float* out = (float*)d_out;
    char* ws = (char*)d_ws;

    unsigned* hist             = (unsigned*)(ws + 0);          // 2048 u32
    unsigned* cnt              = (unsigned*)(ws + 8192);       // 1 u32
    unsigned* thr              = (unsigned*)(ws + 8196);       // 1 u32
    unsigned long long* keys   = (unsigned long long*)(ws + 8704);   // 2048 u64
    unsigned long long* sorted = (unsigned long long*)(ws + 25088);  // 512 u64
    float* cand                = (float*)(ws + 29184);         // 512*7 f32
    unsigned long long* mask   = (unsigned long long*)(ws + 43520);  // 4096 u64

    int nb = (NTOT + 255) / 256;
    k_init<<<1, 256, 0, stream>>>(hist, cnt);
    k_hist<<<nb, 256, 0, stream>>>(p13, p26, p52, hist);
    k_scan<<<1, 256, 0, stream>>>(hist, thr);
    k_compact<<<nb, 256, 0, stream>>>(p13, p26, p52, thr, cnt, keys);
    k_sort<<<1, 1024, 0, stream>>>(cnt, keys, sorted);
    k_decode<<<TOPK, 64, 0, stream>>>(p13, p26, p52, sorted, cand);
    k_mask<<<16, 256, 0, stream>>>(cand, mask);
    k_nms<<<1, 512, 0, stream>>>(cand, mask, out);
}